// Round 8
// baseline (283.105 us; speedup 1.0000x reference)
//
#include <hip/hip_runtime.h>
#include <stdint.h>

// TemporalAttention on MI355X (gfx950).
// Pipeline: convert weights -> transpose+convert x -> QKV GEMM (256^2-tile,
//           3-buf counted-vmcnt pipeline, swizzled LDS, bf16 MFMA)
//           -> per-token attention (MFMA 32x32x16, swapped S^T, in-reg softmax)
//           -> proj GEMM (same template) writing final layout.
// Sizes: B=2, C=512, T=16, HH=32, WW=32 -> N=32768 tokens, M per b = 16384.

#define DEVI __device__ __forceinline__

typedef short bf16x8 __attribute__((ext_vector_type(8)));
typedef float f32x4 __attribute__((ext_vector_type(4)));
typedef float f32x16 __attribute__((ext_vector_type(16)));

DEVI unsigned short f2bf(float f) {
  unsigned int u = __float_as_uint(f);
  unsigned int r = (u + 0x7fffu + ((u >> 16) & 1u)) >> 16;  // RNE
  return (unsigned short)r;
}

DEVI unsigned cvtpk(float lo, float hi) {
  unsigned r;
  asm("v_cvt_pk_bf16_f32 %0, %1, %2" : "=v"(r) : "v"(lo), "v"(hi));
  return r;
}

DEVI bf16x8 pack8(unsigned a, unsigned b, unsigned c, unsigned d) {
  union { unsigned u[4]; bf16x8 v; } t;
  t.u[0] = a; t.u[1] = b; t.u[2] = c; t.u[3] = d;
  return t.v;
}

DEVI void async_load16(const void* g, void* l) {
  __builtin_amdgcn_global_load_lds(
      (const __attribute__((address_space(1))) unsigned int*)g,
      (__attribute__((address_space(3))) unsigned int*)l, 16, 0, 0);
}

// ---------------- weight conversion: fp32 -> bf16, 4 elems/thread ----------
__global__ __launch_bounds__(256) void convert_kernel(
    const float* __restrict__ src, unsigned short* __restrict__ dst, int n4) {
  int i = blockIdx.x * 256 + threadIdx.x;
  if (i >= n4) return;
  const float4 v = ((const float4*)src)[i];
  ushort4 o;
  o.x = f2bf(v.x); o.y = f2bf(v.y); o.z = f2bf(v.z); o.w = f2bf(v.w);
  ((ushort4*)dst)[i] = o;
}

// ---------------- x (b,c,m) fp32 -> xbt (n=b*16384+m, c) bf16 --------------
__global__ __launch_bounds__(256) void transpose_convert(
    const float* __restrict__ x, unsigned short* __restrict__ xbt) {
  __shared__ float tile[32][33];
  const int mb = blockIdx.x, cb = blockIdx.y, b = blockIdx.z;
  const int tx = threadIdx.x & 31, ty = threadIdx.x >> 5;
  const size_t xbase = (size_t)b * 8388608 + (size_t)(cb * 32) * 16384 + (size_t)mb * 32;
#pragma unroll
  for (int i = 0; i < 4; i++)
    tile[ty + i * 8][tx] = x[xbase + (size_t)(ty + i * 8) * 16384 + tx];
  __syncthreads();
  const size_t obase = ((size_t)b * 16384 + (size_t)mb * 32) * 512 + cb * 32;
#pragma unroll
  for (int i = 0; i < 4; i++) {
    const int ro = ty + i * 8;
    xbt[obase + (size_t)ro * 512 + tx] = f2bf(tile[tx][ro]);
  }
}

// ---------------- GEMM v2: Out[row,col] = sum_k A[row,k]*B[col,k] ----------
// BM=BN=256, BK=32, 512 threads = 8 waves (wm 0..1 x wn 0..3), each wave a
// 128x64 C-block via 8x4 frags of mfma_f32_16x16x32_bf16.
// 3 LDS buffers (96 KB), counted vmcnt(4) pipeline (stage t+2 in flight while
// computing t), raw s_barrier (no compiler vmcnt(0) drain), setprio on MFMA.
// LDS swizzle: LDS[r][chunk c] = G[r][c ^ ((r>>1)&3)] (16B chunks, BK=32 row
// = 4 chunks); applied on stage (source pre-permute) and ds_read (same XOR).
// MODE 0: +bias[col], write bf16 at C[row*Nc+col]              (QKV)
// MODE 1: +bias[row], write fp32 at out[b][row][m=col] final layout (proj^T)
template <int MODE, int SWZ>
__global__ __launch_bounds__(512, 2) void gemm_bt2(
    const unsigned short* __restrict__ A, const unsigned short* __restrict__ B,
    const float* __restrict__ bias, void* __restrict__ Cout,
    int ntn, int K, int Nc) {
  __shared__ alignas(16) unsigned short lds3[3][16384];  // [buf][A 8192 | B 8192]
  int bid = blockIdx.x;
  if constexpr (SWZ) bid = (bid & 7) * (gridDim.x >> 3) + (bid >> 3);  // nwg%8==0
  const int tm = bid / ntn, tn = bid % ntn;
  const int tid = threadIdx.x;
  const int lane = tid & 63, wave = tid >> 6;
  const int wm = wave >> 2, wn = wave & 3;
  const int NT = K >> 5;  // BK=32

  const unsigned short* Ab = A + (size_t)tm * 256 * K;
  const unsigned short* Bb = B + (size_t)tn * 256 * K;
  // staging: per inst j: row = j*128 + tid/4, chunk = tid&3; source chunk
  // pre-swizzled so linear LDS write lands the involution.
  const int srow = tid >> 2;                               // 0..127
  const int scol = (((tid & 3) ^ ((tid >> 3) & 3)) << 3);  // elems

  f32x4 acc[8][4];
#pragma unroll
  for (int i = 0; i < 8; i++)
#pragma unroll
    for (int j = 0; j < 4; j++) acc[i][j] = f32x4{0.f, 0.f, 0.f, 0.f};

  auto stage = [&](int t, int b) {
    unsigned short* la = lds3[b];
    unsigned short* lb = lds3[b] + 8192;
    const unsigned short* ga = Ab + (size_t)srow * K + t * 32 + scol;
    const unsigned short* gb = Bb + (size_t)srow * K + t * 32 + scol;
#pragma unroll
    for (int j = 0; j < 2; j++)
      async_load16(ga + (size_t)(j * 128) * K, la + j * 4096 + wave * 512);
#pragma unroll
    for (int j = 0; j < 2; j++)
      async_load16(gb + (size_t)(j * 128) * K, lb + j * 4096 + wave * 512);
  };

  const int rchunk = ((lane >> 4) ^ ((lane >> 1) & 3)) << 3;  // swizzled k-chunk (elems)
  auto compute = [&](int b) {
    const unsigned short* la = lds3[b];
    const unsigned short* lb = lds3[b] + 8192;
    bf16x8 bfr[4], af[8];
#pragma unroll
    for (int ni = 0; ni < 4; ni++) {
      const int R = wn * 64 + ni * 16 + (lane & 15);
      bfr[ni] = *(const bf16x8*)(lb + R * 32 + rchunk);
    }
#pragma unroll
    for (int mi = 0; mi < 8; mi++) {
      const int R = wm * 128 + mi * 16 + (lane & 15);
      af[mi] = *(const bf16x8*)(la + R * 32 + rchunk);
    }
    __builtin_amdgcn_s_setprio(1);
#pragma unroll
    for (int mi = 0; mi < 8; mi++)
#pragma unroll
      for (int ni = 0; ni < 4; ni++)
        acc[mi][ni] = __builtin_amdgcn_mfma_f32_16x16x32_bf16(af[mi], bfr[ni], acc[mi][ni], 0, 0, 0);
    __builtin_amdgcn_s_setprio(0);
  };

  // prologue: two stages in flight, retire the first (4 insts/stage/thread)
  stage(0, 0);
  stage(1, 1);
  asm volatile("s_waitcnt vmcnt(4)" ::: "memory");
  __builtin_amdgcn_s_barrier();
  __builtin_amdgcn_sched_barrier(0);
  for (int t = 0; t < NT; t++) {
    if (t + 2 < NT) stage(t + 2, (t + 2) % 3);
    compute(t % 3);
    if (t + 1 < NT) {
      if (t + 2 < NT) asm volatile("s_waitcnt vmcnt(4)" ::: "memory");
      else            asm volatile("s_waitcnt vmcnt(0)" ::: "memory");
      __builtin_amdgcn_s_barrier();
      __builtin_amdgcn_sched_barrier(0);
    }
  }

  if constexpr (MODE == 0) {
    unsigned short* C = (unsigned short*)Cout;
#pragma unroll
    for (int ni = 0; ni < 4; ni++) {
      const int col = tn * 256 + wn * 64 + ni * 16 + (lane & 15);
      const float bv = bias[col];
#pragma unroll
      for (int mi = 0; mi < 8; mi++) {
        const int row0 = tm * 256 + wm * 128 + mi * 16 + ((lane >> 4) << 2);
#pragma unroll
        for (int r = 0; r < 4; r++)
          C[(size_t)(row0 + r) * Nc + col] = f2bf(acc[mi][ni][r] + bv);
      }
    }
  } else {
    float* C = (float*)Cout;
#pragma unroll
    for (int mi = 0; mi < 8; mi++) {
      const int row0 = tm * 256 + wm * 128 + mi * 16 + ((lane >> 4) << 2);
      const float4 bv4 = *(const float4*)(bias + row0);
      const float* bvp = (const float*)&bv4;
#pragma unroll
      for (int ni = 0; ni < 4; ni++) {
        const int col = tn * 256 + wn * 64 + ni * 16 + (lane & 15);  // token n
        const int bb = col >> 14, m = col & 16383;
        float* dst = C + (size_t)bb * 8388608 + m;
#pragma unroll
        for (int r = 0; r < 4; r++)
          dst[(size_t)(row0 + r) * 16384] = acc[mi][ni][r] + bvp[r];
      }
    }
  }
}

// ---------------- per-token attention via MFMA 32x32x16 --------------------
// (unchanged — validated round 6: total 265 µs, absmax 9.8e-4)
__global__ __launch_bounds__(256) void attn_mfma(
    const unsigned short* __restrict__ qkv, unsigned short* __restrict__ aout) {
  const int wave = threadIdx.x >> 6, lane = threadIdx.x & 63;
  const size_t n = (size_t)blockIdx.x * 4 + wave;
  const unsigned short* base = qkv + n * 1536;  // [q 512][k 512][v 512] bf16
  const int l31 = lane & 31;
  const int hi = lane >> 5;

  bf16x8 aK[2], bQ[2];
  if (hi == 0) {
    const unsigned short* kb = base + 512 + l31;
#pragma unroll
    for (int mt = 0; mt < 2; mt++) {
      unsigned short t[8];
#pragma unroll
      for (int h = 0; h < 8; h++) t[h] = kb[32 * mt + 64 * h];
      aK[mt] = pack8((unsigned)t[0] | ((unsigned)t[1] << 16),
                     (unsigned)t[2] | ((unsigned)t[3] << 16),
                     (unsigned)t[4] | ((unsigned)t[5] << 16),
                     (unsigned)t[6] | ((unsigned)t[7] << 16));
    }
    const unsigned short* qb = base + l31;
#pragma unroll
    for (int nt = 0; nt < 2; nt++) {
      unsigned short t[8];
#pragma unroll
      for (int h = 0; h < 8; h++) t[h] = qb[32 * nt + 64 * h];
      bQ[nt] = pack8((unsigned)t[0] | ((unsigned)t[1] << 16),
                     (unsigned)t[2] | ((unsigned)t[3] << 16),
                     (unsigned)t[4] | ((unsigned)t[5] << 16),
                     (unsigned)t[6] | ((unsigned)t[7] << 16));
    }
  } else {
    const bf16x8 z8 = pack8(0u, 0u, 0u, 0u);
    aK[0] = z8; aK[1] = z8; bQ[0] = z8; bQ[1] = z8;
  }

  bf16x8 aV[4];
  const unsigned short* vb = base + 1024 + (l31 & 7) * 64 + 8 * hi;
#pragma unroll
  for (int kt = 0; kt < 4; kt++)
    aV[kt] = *(const bf16x8*)(vb + 16 * kt);

  f32x16 zz;
#pragma unroll
  for (int i = 0; i < 16; i++) zz[i] = 0.f;
  f32x16 accS[2][2];
#pragma unroll
  for (int mt = 0; mt < 2; mt++)
#pragma unroll
    for (int nt = 0; nt < 2; nt++)
      accS[mt][nt] = __builtin_amdgcn_mfma_f32_32x32x16_bf16(aK[mt], bQ[nt], zz, 0, 0, 0);

#pragma unroll
  for (int mt = 0; mt < 2; mt++)
#pragma unroll
    for (int nt = 0; nt < 2; nt++)
#pragma unroll
      for (int r = 0; r < 16; r++)
        accS[mt][nt][r] = __expf(accS[mt][nt][r] * 0.125f);

  float inv[2];
#pragma unroll
  for (int nt = 0; nt < 2; nt++) {
    float s = 0.f;
#pragma unroll
    for (int mt = 0; mt < 2; mt++)
#pragma unroll
      for (int r = 0; r < 16; r++) s += accS[mt][nt][r];
    s += __shfl_xor(s, 32, 64);
    inv[nt] = 1.f / s;
  }

  unsigned short* outp = aout + n * 512 + l31 + 256 * hi;
#pragma unroll
  for (int nt = 0; nt < 2; nt++) {
    bf16x8 bP[4];
#pragma unroll
    for (int kt = 0; kt < 4; kt++) {
      const int mt = kt >> 1;
      const int o = (kt & 1) * 8;
      const unsigned U = cvtpk(accS[mt][nt][o + 0], accS[mt][nt][o + 1]);
      const unsigned V = cvtpk(accS[mt][nt][o + 2], accS[mt][nt][o + 3]);
      const unsigned W = cvtpk(accS[mt][nt][o + 4], accS[mt][nt][o + 5]);
      const unsigned Z = cvtpk(accS[mt][nt][o + 6], accS[mt][nt][o + 7]);
      const unsigned Us = __shfl_xor(U, 32, 64);
      const unsigned Vs = __shfl_xor(V, 32, 64);
      const unsigned Ws = __shfl_xor(W, 32, 64);
      const unsigned Zs = __shfl_xor(Z, 32, 64);
      bP[kt] = pack8(hi ? Ws : U, hi ? Zs : V, hi ? W : Us, hi ? Z : Vs);
    }
    f32x16 accO = zz;
#pragma unroll
    for (int kt = 0; kt < 4; kt++)
      accO = __builtin_amdgcn_mfma_f32_32x32x16_bf16(aV[kt], bP[kt], accO, 0, 0, 0);
#pragma unroll
    for (int r = 0; r < 4; r++)
      outp[32 * nt + 64 * r] = f2bf(accO[r] * inv[nt]);
  }
}

// ---------------- launch ---------------------------------------------------
extern "C" void kernel_launch(void* const* d_in, const int* in_sizes, int n_in,
                              void* d_out, int out_size, void* d_ws, size_t ws_size,
                              hipStream_t stream) {
  const float* x      = (const float*)d_in[0];
  const float* qkv_w  = (const float*)d_in[1];
  const float* qkv_b  = (const float*)d_in[2];
  const float* proj_w = (const float*)d_in[3];
  const float* proj_b = (const float*)d_in[4];

  char* ws = (char*)d_ws;
  unsigned short* xbt     = (unsigned short*)(ws);              // 32 MB; reused as aout later
  unsigned short* qkvw_b  = (unsigned short*)(ws + 33554432);   // 1.5 MB
  unsigned short* projw_b = (unsigned short*)(ws + 35127296);   // 0.5 MB
  unsigned short* qkvo    = (unsigned short*)(ws + 35651584);   // 96 MB
  unsigned short* aout    = xbt;                                // xbt dead after GEMM1
  // total ws use: 136,314,880 B (130.3 MB)

  convert_kernel<<<768, 256, 0, stream>>>(qkv_w, qkvw_b, 196608);
  convert_kernel<<<256, 256, 0, stream>>>(proj_w, projw_b, 65536);
  transpose_convert<<<dim3(512, 16, 2), 256, 0, stream>>>(x, xbt);
  // QKV: Out[n, j] = sum_c xbt[n,c]*qkv_w[j,c] + qkv_b[j]  (M=32768, N=1536)
  gemm_bt2<0, 1><<<128 * 6, 512, 0, stream>>>(xbt, qkvw_b, qkv_b, qkvo, 6, 512, 1536);
  attn_mfma<<<8192, 256, 0, stream>>>(qkvo, aout);
  // Proj^T: T[j, n] = sum_c proj_w[j,c]*aout[n,c] + proj_b[j] -> out[b][j][m]
  gemm_bt2<1, 1><<<2 * 128, 512, 0, stream>>>(projw_b, aout, proj_b, d_out, 128, 512, 0);
}